// Round 1
// baseline (1147.886 us; speedup 1.0000x reference)
//
#include <hip/hip_runtime.h>
#include <math.h>

#define D 256
#define K 1024
#define NROWS 65536
#define R 16
#define MARGIN 0.125f

// ---------------- helpers ----------------
__device__ inline float wave_sum_f(float v){
  #pragma unroll
  for (int off = 32; off; off >>= 1) v += __shfl_down(v, off);
  return v;
}
__device__ inline double wave_sum_d(double v){
  #pragma unroll
  for (int off = 32; off; off >>= 1) v += __shfl_down(v, off);
  return v;
}

// ---------------- prep: codebook transpose + column norms ----------------
// cb is [D][K] row-major. Block k: thread t = d. Writes cT[k][d] and cnorm[k].
__global__ __launch_bounds__(256) void prep_codebook(const float* __restrict__ cb,
                                                     float* __restrict__ cT,
                                                     float* __restrict__ cnorm){
  const int k = blockIdx.x;
  const int t = threadIdx.x;
  const int w = t >> 6, lane = t & 63;
  float v = cb[(size_t)t * K + k];
  cT[(size_t)k * D + t] = v;
  float s = wave_sum_f(v * v);
  __shared__ float red[4];
  if (lane == 0) red[w] = s;
  __syncthreads();
  if (t == 0) cnorm[k] = red[0] + red[1] + red[2] + red[3];
}

// ---------------- prep: row norms, one wave per row ----------------
__global__ __launch_bounds__(256) void row_norms(const float* __restrict__ x,
                                                 float* __restrict__ xnorm){
  const int t = threadIdx.x;
  const int w = t >> 6, lane = t & 63;
  const size_t n = (size_t)blockIdx.x * 4 + w;
  const float4 v = *(const float4*)(x + n * D + lane * 4);
  float s = v.x*v.x + v.y*v.y + v.z*v.z + v.w*v.w;
  s = wave_sum_f(s);
  if (lane == 0) xnorm[n] = s;
}

// ---------------- main: dist GEMM + argmin(+fp64 refine) + soft counts + loss ----------------
__global__ __launch_bounds__(256) void vq_main(
    const float* __restrict__ x, const float* __restrict__ cb,
    const float* __restrict__ cT, const float* __restrict__ cnorm,
    const float* __restrict__ xnorm,
    float* __restrict__ q_out, float* __restrict__ soft,
    double* __restrict__ loss_acc)
{
  __shared__ float xs[R][D];                 // 16 KB x tile
  __shared__ float redv[4], reds[4];
  __shared__ int   redi[4];
  __shared__ float rowmin[R];
  __shared__ float rowrsum[R];
  __shared__ int   rowbest[R];
  __shared__ float rxn[R];
  __shared__ int   ncand;
  __shared__ int   cand_rk[256];
  __shared__ double cand_d[256];
  __shared__ double redd[4];

  const int t = threadIdx.x;
  const int w = t >> 6, lane = t & 63;
  const size_t base = (size_t)blockIdx.x * R;

  // stage x tile (coalesced float4)
  {
    const float4* xg = (const float4*)(x + base * D);
    float4* xs4 = (float4*)xs;
    #pragma unroll
    for (int i = 0; i < R * D / 4 / 256; i++)
      xs4[t + i * 256] = xg[t + i * 256];
  }
  if (t < R) rxn[t] = xnorm[base + t];
  if (t == 0) ncand = 0;
  __syncthreads();

  // ---- sim accumulation: thread owns columns k0..k0+3
  const int k0 = t * 4;
  float4 acc[R];
  #pragma unroll
  for (int r = 0; r < R; r++) acc[r] = make_float4(0.f, 0.f, 0.f, 0.f);

  for (int d = 0; d < D; d += 4) {
    const float4 c0 = *(const float4*)(cb + (size_t)(d + 0) * K + k0);
    const float4 c1 = *(const float4*)(cb + (size_t)(d + 1) * K + k0);
    const float4 c2 = *(const float4*)(cb + (size_t)(d + 2) * K + k0);
    const float4 c3 = *(const float4*)(cb + (size_t)(d + 3) * K + k0);
    #pragma unroll
    for (int r = 0; r < R; r++) {
      const float4 xv = *(const float4*)&xs[r][d];   // wave-uniform broadcast
      acc[r].x = fmaf(xv.w, c3.x, fmaf(xv.z, c2.x, fmaf(xv.y, c1.x, fmaf(xv.x, c0.x, acc[r].x))));
      acc[r].y = fmaf(xv.w, c3.y, fmaf(xv.z, c2.y, fmaf(xv.y, c1.y, fmaf(xv.x, c0.y, acc[r].y))));
      acc[r].z = fmaf(xv.w, c3.z, fmaf(xv.z, c2.z, fmaf(xv.y, c1.z, fmaf(xv.x, c0.z, acc[r].z))));
      acc[r].w = fmaf(xv.w, c3.w, fmaf(xv.z, c2.w, fmaf(xv.y, c1.w, fmaf(xv.x, c0.w, acc[r].w))));
    }
  }

  // ---- convert to squared distances
  const float4 cn = *(const float4*)(cnorm + k0);
  #pragma unroll
  for (int r = 0; r < R; r++) {
    const float xn = rxn[r];
    float4 dv;
    dv.x = xn + cn.x - 2.0f * acc[r].x;
    dv.y = xn + cn.y - 2.0f * acc[r].y;
    dv.z = xn + cn.z - 2.0f * acc[r].z;
    dv.w = xn + cn.w - 2.0f * acc[r].w;
    acc[r] = dv;
  }

  // ---- per-row reductions: fp32 min(+idx) and sum((1/d)^2)
  #pragma unroll
  for (int r = 0; r < R; r++) {
    const float4 dv = acc[r];
    float mv = dv.x; int mi = k0;
    if (dv.y < mv) { mv = dv.y; mi = k0 + 1; }
    if (dv.z < mv) { mv = dv.z; mi = k0 + 2; }
    if (dv.w < mv) { mv = dv.w; mi = k0 + 3; }
    float i0 = 1.0f / dv.x, i1 = 1.0f / dv.y, i2 = 1.0f / dv.z, i3 = 1.0f / dv.w;
    float ss = i0*i0 + i1*i1 + i2*i2 + i3*i3;
    #pragma unroll
    for (int off = 32; off; off >>= 1) {
      float ov = __shfl_down(mv, off);
      int   oi = __shfl_down(mi, off);
      ss += __shfl_down(ss, off);
      if (ov < mv) { mv = ov; mi = oi; }
    }
    if (lane == 0) { redv[w] = mv; redi[w] = mi; reds[w] = ss; }
    __syncthreads();
    if (t == 0) {
      float m = redv[0]; int i = redi[0];
      #pragma unroll
      for (int q = 1; q < 4; q++) if (redv[q] < m) { m = redv[q]; i = redi[q]; }
      rowmin[r] = m; rowbest[r] = i;
      rowrsum[r] = reds[0] + reds[1] + reds[2] + reds[3];
    }
    __syncthreads();
  }

  // ---- soft counts write (coalesced float4 per row)
  #pragma unroll
  for (int r = 0; r < R; r++) {
    const float rs = 1.0f / rowrsum[r];
    const float4 dv = acc[r];
    float4 o;
    float iv;
    iv = 1.0f / dv.x; o.x = iv * iv * rs;
    iv = 1.0f / dv.y; o.y = iv * iv * rs;
    iv = 1.0f / dv.z; o.z = iv * iv * rs;
    iv = 1.0f / dv.w; o.w = iv * iv * rs;
    *(float4*)(soft + (base + r) * (size_t)K + k0) = o;
  }

  // ---- collect near-min candidates for fp64-exact argmin
  #pragma unroll
  for (int r = 0; r < R; r++) {
    const float lim = rowmin[r] + MARGIN;
    const float4 dv = acc[r];
    const float dvals[4] = {dv.x, dv.y, dv.z, dv.w};
    #pragma unroll
    for (int j = 0; j < 4; j++) {
      if (dvals[j] <= lim) {
        int p = atomicAdd(&ncand, 1);
        if (p < 256) cand_rk[p] = (r << 10) | (k0 + j);
      }
    }
  }
  __syncthreads();

  // ---- wave-cooperative fp64 exact distance per candidate
  const int nc = min(ncand, 256);
  for (int c = w; c < nc; c += 4) {
    const int rk = cand_rk[c];
    const int r = rk >> 10, k = rk & 1023;
    const float4 xv = *(const float4*)&xs[r][lane * 4];
    const float4 cv = *(const float4*)(cT + (size_t)k * D + lane * 4);
    double s = 0.0, dx;
    dx = (double)xv.x - (double)cv.x; s += dx * dx;
    dx = (double)xv.y - (double)cv.y; s += dx * dx;
    dx = (double)xv.z - (double)cv.z; s += dx * dx;
    dx = (double)xv.w - (double)cv.w; s += dx * dx;
    s = wave_sum_d(s);
    if (lane == 0) cand_d[c] = s;
  }
  __syncthreads();

  if (t < R) {
    double best = 1e300; int bi = 1 << 20;
    for (int c = 0; c < nc; c++) {
      const int rk = cand_rk[c];
      if ((rk >> 10) == t) {
        const int k = rk & 1023;
        const double dvd = cand_d[c];
        if (dvd < best || (dvd == best && k < bi)) { best = dvd; bi = k; }
      }
    }
    rowbest[t] = bi;
  }
  __syncthreads();

  // ---- quantized write + fp64 loss accumulation
  double lp = 0.0;
  #pragma unroll
  for (int r = 0; r < R; r++) {
    const int bk = rowbest[r];
    const float v = cT[(size_t)bk * D + t];
    q_out[(base + r) * (size_t)D + t] = v;
    const float dfl = v - xs[r][t];
    lp += (double)dfl * (double)dfl;
  }
  lp = wave_sum_d(lp);
  if (lane == 0) redd[w] = lp;
  __syncthreads();
  if (t == 0) atomicAdd(loss_acc, redd[0] + redd[1] + redd[2] + redd[3]);
}

// ---------------- finalize loss ----------------
__global__ void finalize_loss(const double* __restrict__ acc, float* __restrict__ out_loss){
  // commitment (BETA=0.25) + codebook loss; stop_gradient is a forward no-op
  out_loss[0] = (float)(1.25 * acc[0] / (double)((size_t)NROWS * D));
}

extern "C" void kernel_launch(void* const* d_in, const int* in_sizes, int n_in,
                              void* d_out, int out_size, void* d_ws, size_t ws_size,
                              hipStream_t stream) {
  const float* x  = (const float*)d_in[0];   // [64,1024,256] -> [65536,256]
  const float* cb = (const float*)d_in[1];   // [256,1024]

  float* out      = (float*)d_out;
  float* q_out    = out;                                    // 16777216
  float* soft     = out + (size_t)NROWS * D;                // 67108864
  float* loss_out = out + (size_t)NROWS * D + (size_t)NROWS * K; // 1

  char* ws = (char*)d_ws;
  double* acc  = (double*)ws;                       // 8 B
  float* cnorm = (float*)(ws + 256);                // 4 KB
  float* cT    = (float*)(ws + 8192);               // 1 MB
  float* xnorm = (float*)(ws + 8192 + 1048576);     // 256 KB

  hipMemsetAsync(acc, 0, sizeof(double), stream);
  prep_codebook<<<K, 256, 0, stream>>>(cb, cT, cnorm);
  row_norms<<<NROWS / 4, 256, 0, stream>>>(x, xnorm);
  vq_main<<<NROWS / R, 256, 0, stream>>>(x, cb, cT, cnorm, xnorm, q_out, soft, acc);
  finalize_loss<<<1, 1, 0, stream>>>(acc, loss_out);
}

// Round 2
// 650.583 us; speedup vs baseline: 1.7644x; 1.7644x over previous
//
#include <hip/hip_runtime.h>
#include <math.h>

#define D 256
#define K 1024
#define NROWS 65536
#define MARGIN 0.125f

typedef __bf16 bf16x8 __attribute__((ext_vector_type(8)));
typedef float f32x4 __attribute__((ext_vector_type(4)));

// async global->LDS, 16B per lane; lds base must be wave-uniform, lane i lands at base + i*16
#define GL2LDS16(g, l) __builtin_amdgcn_global_load_lds( \
    (const __attribute__((address_space(1))) char*)(const void*)(g), \
    (__attribute__((address_space(3))) char*)(void*)(l), 16, 0, 0)

__device__ inline float wave_sum_f(float v){
  #pragma unroll
  for (int off = 32; off; off >>= 1) v += __shfl_down(v, off);
  return v;
}
__device__ inline double wave_sum_d(double v){
  #pragma unroll
  for (int off = 32; off; off >>= 1) v += __shfl_down(v, off);
  return v;
}

// ---------------- pass 0a: split x into bf16 hi/lo + row norms ----------------
__global__ __launch_bounds__(256) void split_rows(const float* __restrict__ x,
                                                  __bf16* __restrict__ xh,
                                                  __bf16* __restrict__ xl,
                                                  float* __restrict__ xnorm){
  const int t = threadIdx.x;
  const int w = t >> 6, lane = t & 63;
  const size_t row = (size_t)blockIdx.x * 4 + w;
  const float4 v = *(const float4*)(x + row * D + lane * 4);
  float s = v.x*v.x + v.y*v.y + v.z*v.z + v.w*v.w;
  s = wave_sum_f(s);
  union { __bf16 b[4]; short4 s4; } uh, ul;
  const float vv[4] = {v.x, v.y, v.z, v.w};
  #pragma unroll
  for (int j = 0; j < 4; j++){
    __bf16 h = (__bf16)vv[j];
    uh.b[j] = h;
    ul.b[j] = (__bf16)(vv[j] - (float)h);
  }
  *(short4*)(xh + row * D + lane * 4) = uh.s4;
  *(short4*)(xl + row * D + lane * 4) = ul.s4;
  if (lane == 0) xnorm[row] = s;
}

// ---------------- pass 0b: codebook transpose (fp32 + bf16 hi/lo) + col norms ----------------
__global__ __launch_bounds__(256) void prep_codebook(const float* __restrict__ cb,
                                                     float* __restrict__ cT,
                                                     __bf16* __restrict__ ch,
                                                     __bf16* __restrict__ cl,
                                                     float* __restrict__ cnorm){
  const int k = blockIdx.x;
  const int t = threadIdx.x;
  const int w = t >> 6, lane = t & 63;
  float v = cb[(size_t)t * K + k];
  cT[(size_t)k * D + t] = v;
  __bf16 h = (__bf16)v;
  ch[(size_t)k * D + t] = h;
  cl[(size_t)k * D + t] = (__bf16)(v - (float)h);
  float s = wave_sum_f(v * v);
  __shared__ float red[4];
  if (lane == 0) red[w] = s;
  __syncthreads();
  if (t == 0) cnorm[k] = red[0] + red[1] + red[2] + red[3];
}

// ---------------- pass 1: split-bf16 MFMA distance GEMM ----------------
// block: 64 rows x 1024 codes (code-tiles of 128). Writes dist (fp32) + per-row {min, sum(1/d^2)}.
__global__ __launch_bounds__(256) void vq_mfma(
    const __bf16* __restrict__ xh, const __bf16* __restrict__ xl,
    const __bf16* __restrict__ ch, const __bf16* __restrict__ cl,
    const float* __restrict__ cnorm, const float* __restrict__ xnorm,
    float* __restrict__ distbuf, float2* __restrict__ rowstat)
{
  __shared__ __bf16 Ah[2][64*32];    // 8 KB
  __shared__ __bf16 Al[2][64*32];    // 8 KB
  __shared__ __bf16 Bh[2][128*32];   // 16 KB
  __shared__ __bf16 Bl[2][128*32];   // 16 KB  -> 48 KB total, 3 blocks/CU

  const int t = threadIdx.x, w = t >> 6, lane = t & 63;
  const int m = lane & 15, quad = lane >> 4;
  const size_t base = (size_t)blockIdx.x * 64;
  const int rlo = (w & 1) * 32;          // wave's row slice
  const int cw  = (w >> 1) * 64;         // wave's code slice within 128-tile

  // hoist xnorm for the 8 rows this lane's accumulators touch
  float xn[2][4];
  #pragma unroll
  for (int rt = 0; rt < 2; rt++)
    #pragma unroll
    for (int j = 0; j < 4; j++)
      xn[rt][j] = xnorm[base + rlo + rt*16 + quad*4 + j];

  float minv[2][4], sums[2][4];
  #pragma unroll
  for (int rt = 0; rt < 2; rt++)
    #pragma unroll
    for (int j = 0; j < 4; j++){ minv[rt][j] = 1e30f; sums[rt][j] = 0.f; }

  auto stageA = [&](int buf, int chunk){
    const int e = t, row = e >> 2, part = e & 3;
    const size_t go = ((base + row) << 8) + chunk*32 + part*8;
    GL2LDS16(xh + go, &Ah[buf][w * 512]);
    GL2LDS16(xl + go, &Al[buf][w * 512]);
  };
  auto stageB = [&](int buf, int ct, int chunk){
    #pragma unroll
    for (int i = 0; i < 2; i++){
      const int e = t + i*256, code = e >> 2, part = e & 3;
      const size_t go = (((size_t)ct*128 + code) << 8) + chunk*32 + part*8;
      GL2LDS16(ch + go, &Bh[buf][(w*64 + i*256) * 8]);
      GL2LDS16(cl + go, &Bl[buf][(w*64 + i*256) * 8]);
    }
  };

  int cur = 0;
  stageA(0, 0); stageB(0, 0, 0);

  for (int ct = 0; ct < 8; ct++){
    f32x4 acc[2][4];
    #pragma unroll
    for (int rt = 0; rt < 2; rt++)
      #pragma unroll
      for (int c = 0; c < 4; c++) acc[rt][c] = (f32x4){0.f, 0.f, 0.f, 0.f};

    for (int chunk = 0; chunk < 8; chunk++){
      __syncthreads();   // staged buf[cur] landed (vmcnt drain); buf[cur^1] free to restage
      int nct = ct, nch = chunk + 1;
      if (nch == 8){ nch = 0; nct = ct + 1; }
      if (nct < 8){ stageA(cur ^ 1, nch); stageB(cur ^ 1, nct, nch); }

      bf16x8 ah[2], al[2], bh[4], bl[4];
      #pragma unroll
      for (int rt = 0; rt < 2; rt++){
        const int ro = (rlo + rt*16 + m) * 32 + quad * 8;
        ah[rt] = *(const bf16x8*)&Ah[cur][ro];
        al[rt] = *(const bf16x8*)&Al[cur][ro];
      }
      #pragma unroll
      for (int c = 0; c < 4; c++){
        const int co = (cw + c*16 + m) * 32 + quad * 8;
        bh[c] = *(const bf16x8*)&Bh[cur][co];
        bl[c] = *(const bf16x8*)&Bl[cur][co];
      }
      #pragma unroll
      for (int rt = 0; rt < 2; rt++)
        #pragma unroll
        for (int c = 0; c < 4; c++){
          acc[rt][c] = __builtin_amdgcn_mfma_f32_16x16x32_bf16(ah[rt], bh[c], acc[rt][c], 0, 0, 0);
          acc[rt][c] = __builtin_amdgcn_mfma_f32_16x16x32_bf16(ah[rt], bl[c], acc[rt][c], 0, 0, 0);
          acc[rt][c] = __builtin_amdgcn_mfma_f32_16x16x32_bf16(al[rt], bh[c], acc[rt][c], 0, 0, 0);
        }
      cur ^= 1;
    }

    // epilogue for this 128-code tile (register-local, no barrier)
    float cn[4];
    #pragma unroll
    for (int c = 0; c < 4; c++) cn[c] = cnorm[ct*128 + cw + c*16 + m];
    #pragma unroll
    for (int rt = 0; rt < 2; rt++)
      #pragma unroll
      for (int c = 0; c < 4; c++)
        #pragma unroll
        for (int j = 0; j < 4; j++){
          const float d = xn[rt][j] + cn[c] - 2.0f * acc[rt][c][j];
          const size_t rg = base + rlo + rt*16 + quad*4 + j;
          distbuf[rg * K + ct*128 + cw + c*16 + m] = d;
          minv[rt][j] = fminf(minv[rt][j], d);
          const float iv = 1.0f / d;
          sums[rt][j] += iv * iv;
        }
  }

  // cross-lane (within 16-lane quad group) reduction of per-row min/sum
  #pragma unroll
  for (int mask = 1; mask <= 8; mask <<= 1)
    #pragma unroll
    for (int rt = 0; rt < 2; rt++)
      #pragma unroll
      for (int j = 0; j < 4; j++){
        const float om = __shfl_xor(minv[rt][j], mask);
        const float os = __shfl_xor(sums[rt][j], mask);
        minv[rt][j] = fminf(minv[rt][j], om);
        sums[rt][j] += os;
      }

  __syncthreads();                       // all MFMA LDS reads done; safe to reuse Bh
  float2* scratch = (float2*)&Bh[0][0];  // [64 rows][2 wave-slots]
  if (m == 0){
    #pragma unroll
    for (int rt = 0; rt < 2; rt++)
      #pragma unroll
      for (int j = 0; j < 4; j++){
        const int rloc = rlo + rt*16 + quad*4 + j;
        scratch[rloc*2 + (w >> 1)] = make_float2(minv[rt][j], sums[rt][j]);
      }
  }
  __syncthreads();
  if (t < 64){
    const float2 a = scratch[t*2], b = scratch[t*2 + 1];
    rowstat[base + t] = make_float2(fminf(a.x, b.x), a.y + b.y);
  }
}

// ---------------- pass 2: normalize in-place + fp64-refined argmin + quantize + loss ----------------
__global__ __launch_bounds__(256) void vq_finish(
    const float* __restrict__ x, const float* __restrict__ cT,
    const float2* __restrict__ rowstat,
    float* __restrict__ soft,      // in: dist, out: normalized soft counts (in-place)
    float* __restrict__ q_out, double* __restrict__ loss_acc)
{
  __shared__ int   ncand;
  __shared__ int   cand_rk[256];
  __shared__ double cand_d[256];
  __shared__ int   rowbest[16];
  __shared__ double bestd[16];
  __shared__ float lim_s[16], rs_s[16];

  const int t = threadIdx.x, w = t >> 6, lane = t & 63;
  const size_t base = (size_t)blockIdx.x * 16;

  if (t < 16){
    const float2 st = rowstat[base + t];
    lim_s[t] = st.x + MARGIN;
    rs_s[t]  = 1.0f / st.y;
  }
  if (t == 0) ncand = 0;
  __syncthreads();

  for (int r = 0; r < 16; r++){
    const size_t off = (base + r) * (size_t)K + t * 4;
    const float4 dv = *(const float4*)(soft + off);
    const float lim = lim_s[r], rs = rs_s[r];
    float4 o; float iv;
    iv = 1.0f / dv.x; o.x = iv * iv * rs;
    iv = 1.0f / dv.y; o.y = iv * iv * rs;
    iv = 1.0f / dv.z; o.z = iv * iv * rs;
    iv = 1.0f / dv.w; o.w = iv * iv * rs;
    *(float4*)(soft + off) = o;
    const float dvals[4] = {dv.x, dv.y, dv.z, dv.w};
    #pragma unroll
    for (int j = 0; j < 4; j++)
      if (dvals[j] <= lim){
        const int p = atomicAdd(&ncand, 1);
        if (p < 256) cand_rk[p] = (r << 10) | (t*4 + j);
      }
  }
  __syncthreads();

  const int nc = min(ncand, 256);
  for (int c = w; c < nc; c += 4){
    const int rk = cand_rk[c];
    const int r = rk >> 10, k = rk & 1023;
    const float4 xv = *(const float4*)(x  + (base + r) * (size_t)D + lane*4);
    const float4 cv = *(const float4*)(cT + (size_t)k * D + lane*4);
    double s = 0.0, dx;
    dx = (double)xv.x - (double)cv.x; s += dx * dx;
    dx = (double)xv.y - (double)cv.y; s += dx * dx;
    dx = (double)xv.z - (double)cv.z; s += dx * dx;
    dx = (double)xv.w - (double)cv.w; s += dx * dx;
    s = wave_sum_d(s);
    if (lane == 0) cand_d[c] = s;
  }
  __syncthreads();

  if (t < 16){
    double best = 1e300; int bi = 1 << 20;
    for (int c = 0; c < nc; c++){
      const int rk = cand_rk[c];
      if ((rk >> 10) == t){
        const int k = rk & 1023;
        const double dd = cand_d[c];
        if (dd < best || (dd == best && k < bi)){ best = dd; bi = k; }
      }
    }
    rowbest[t] = bi; bestd[t] = best;
  }
  __syncthreads();

  #pragma unroll
  for (int r = 0; r < 16; r++){
    const float q = cT[(size_t)rowbest[r] * D + t];
    q_out[(base + r) * (size_t)D + t] = q;
  }
  if (t == 0){
    double s = 0.0;
    #pragma unroll
    for (int r = 0; r < 16; r++) s += bestd[r];
    atomicAdd(loss_acc, s);
  }
}

// ---------------- finalize loss ----------------
__global__ void finalize_loss(const double* __restrict__ acc, float* __restrict__ out_loss){
  out_loss[0] = (float)(1.25 * acc[0] / (double)((size_t)NROWS * D));
}

extern "C" void kernel_launch(void* const* d_in, const int* in_sizes, int n_in,
                              void* d_out, int out_size, void* d_ws, size_t ws_size,
                              hipStream_t stream) {
  const float* x  = (const float*)d_in[0];   // [65536,256]
  const float* cb = (const float*)d_in[1];   // [256,1024]

  float* out      = (float*)d_out;
  float* q_out    = out;                                          // 16777216
  float* soft     = out + (size_t)NROWS * D;                      // 67108864 (dist in pass1, soft in pass2)
  float* loss_out = out + (size_t)NROWS * D + (size_t)NROWS * K;  // 1

  char* ws = (char*)d_ws;
  double*  acc     = (double*)ws;                       // @0
  float*   cnorm   = (float*)(ws + 4096);               // 4 KB
  float*   xnorm   = (float*)(ws + (1u<<20));           // 256 KB
  float2*  rowstat = (float2*)(ws + (2u<<20));          // 512 KB
  float*   cT      = (float*)(ws + (3u<<20));           // 1 MB
  __bf16*  ch      = (__bf16*)(ws + (4u<<20));          // 512 KB
  __bf16*  cl      = (__bf16*)(ws + 4718592u);          // 512 KB
  __bf16*  xh      = (__bf16*)(ws + 5242880u);          // 32 MB
  __bf16*  xl      = (__bf16*)(ws + 38797312u);         // 32 MB  (total ~69 MB)

  hipMemsetAsync(acc, 0, sizeof(double), stream);
  split_rows<<<NROWS / 4, 256, 0, stream>>>(x, xh, xl, xnorm);
  prep_codebook<<<K, 256, 0, stream>>>(cb, cT, ch, cl, cnorm);
  vq_mfma<<<NROWS / 64, 256, 0, stream>>>(xh, xl, ch, cl, cnorm, xnorm, soft, rowstat);
  vq_finish<<<NROWS / 16, 256, 0, stream>>>(x, cT, rowstat, soft, q_out, acc);
  finalize_loss<<<1, 1, 0, stream>>>(acc, loss_out);
}